// Round 1
// baseline (114.002 us; speedup 1.0000x reference)
//
#include <hip/hip_runtime.h>
#include <hip/hip_bf16.h>

#define SCALE (1.0f/16.0f)

typedef __attribute__((ext_vector_type(8))) short short8;
typedef __attribute__((ext_vector_type(4))) float f32x4;

// ---------------- K1: transpose features [C=256][4096] -> [4096][256] ----------------
__global__ void k_transpose(const float* __restrict__ feat, float* __restrict__ featT) {
    __shared__ float t[64][65];
    int cb = (blockIdx.x >> 6) << 6;      // c base (0,64,128,192)
    int pb = (blockIdx.x & 63) << 6;      // p base (0..4032 step 64)
    int lx = threadIdx.x & 63, ly = threadIdx.x >> 6;  // ly in 0..3
#pragma unroll
    for (int i = 0; i < 16; ++i) {
        int cl = i*4 + ly;
        t[cl][lx] = feat[(size_t)(cb + cl) * 4096 + pb + lx];
    }
    __syncthreads();
#pragma unroll
    for (int i = 0; i < 16; ++i) {
        int pl = i*4 + ly;
        featT[(size_t)(pb + pl) * 256 + cb + lx] = t[lx][pl];
    }
}

// ---------------- K1b: w_fuse f32 -> bf16 ----------------
__global__ void k_cvt(const float* __restrict__ wf, __hip_bfloat16* __restrict__ wfb, int n) {
    int i = blockIdx.x * blockDim.x + threadIdx.x;
    if (i < n) wfb[i] = __float2bfloat16(wf[i]);
}

// ---------------- K2: context boxes + ROIAlignV2 -> A [6272][2048] bf16 ----------------
// block = one context box b in [0,1024); thread = channel c
__global__ void k_pool(const float* __restrict__ featT, const float* __restrict__ boxes,
                       __hip_bfloat16* __restrict__ Ap) {
    int b  = blockIdx.x;
    int off = b >> 7;       // which of 8 context offsets
    int nb  = b & 127;      // original box index
    int n   = (off << 4) + (nb >> 3);   // output "row group" after reshape
    int j   = nb & 7;                   // k-block index
    int c   = threadIdx.x;

    float x1 = boxes[nb*4+0], y1 = boxes[nb*4+1];
    float x2 = boxes[nb*4+2], y2 = boxes[nb*4+3];
    float w3 = (x2 - x1) * (1.f/3.f);
    float h3 = (y2 - y1) * (1.f/3.f);
    // offset order from reference: (i,j) over 3x3 skipping center, i-major
    const int OI[8] = {0,0,0,1,1,2,2,2};
    const int OJ[8] = {0,1,2,0,2,0,1,2};
    float cx1 = x1 + OJ[off]*w3;
    float cy1 = y1 + OI[off]*h3;

    float rx1 = cx1*SCALE - 0.5f;
    float ry1 = cy1*SCALE - 0.5f;
    float bw = ((cx1 + w3)*SCALE - 0.5f - rx1) * (1.f/7.f);
    float bh = ((cy1 + h3)*SCALE - 0.5f - ry1) * (1.f/7.f);

    size_t outbase = ((size_t)n * 49) * 2048 + (size_t)j * 256 + c;

    for (int h = 0; h < 7; ++h) {
        for (int w = 0; w < 7; ++w) {
            float s = 0.f;
#pragma unroll
            for (int sy = 0; sy < 2; ++sy) {
                float y = ry1 + ((float)h + 0.25f + 0.5f*(float)sy) * bh;
                bool vy = (y >= -1.f) && (y <= 64.f);
                float yc = fminf(fmaxf(y, 0.f), 63.f);
                float ylf = fminf(floorf(yc), 62.f);
                int   yl  = (int)ylf;
                float fy  = yc - ylf;
#pragma unroll
                for (int sx = 0; sx < 2; ++sx) {
                    float x = rx1 + ((float)w + 0.25f + 0.5f*(float)sx) * bw;
                    bool vx = (x >= -1.f) && (x <= 64.f);
                    float xc = fminf(fmaxf(x, 0.f), 63.f);
                    float xlf = fminf(floorf(xc), 62.f);
                    int   xl  = (int)xlf;
                    float fx  = xc - xlf;

                    const float* p00 = featT + ((size_t)(yl*64 + xl) * 256 + c);
                    float f00 = p00[0];
                    float f01 = p00[256];
                    float f10 = p00[64*256];
                    float f11 = p00[64*256 + 256];
                    float v = f00*(1.f-fy)*(1.f-fx) + f01*(1.f-fy)*fx
                            + f10*fy*(1.f-fx)       + f11*fy*fx;
                    if (vy && vx) s += v;
                }
            }
            Ap[outbase + (size_t)(h*7 + w) * 2048] = __float2bfloat16(s * 0.25f);
        }
    }
}

// ---------------- K3: GEMM out[m][o] = relu(sum_k A[m][k]*wf[o][k] + b[o]) ----------------
// M=6272, N=256, K=2048. 1-wave blocks: 32 m x 64 o per wave.
// mfma(wfrag, afrag, acc): D rows = o (row=(l>>4)*4+jr), cols = m (col=l&15)
__global__ void k_gemm(const __hip_bfloat16* __restrict__ Ap,
                       const __hip_bfloat16* __restrict__ wfb,
                       const float* __restrict__ bfuse,
                       float* __restrict__ out) {
    int l  = threadIdx.x;          // 0..63
    int m0 = blockIdx.x * 32;
    int o0 = blockIdx.y * 64;
    int r = l & 15, q = l >> 4;    // q in 0..3

    f32x4 acc[4][2];
#pragma unroll
    for (int oi = 0; oi < 4; ++oi)
#pragma unroll
        for (int mi = 0; mi < 2; ++mi) acc[oi][mi] = (f32x4){0.f,0.f,0.f,0.f};

    const __hip_bfloat16* wp = wfb + (size_t)(o0 + r) * 2048 + q * 8;
    const __hip_bfloat16* ap = Ap  + (size_t)(m0 + r) * 2048 + q * 8;

    for (int kt = 0; kt < 64; ++kt) {
        short8 wfr[4], afr[2];
#pragma unroll
        for (int oi = 0; oi < 4; ++oi)
            wfr[oi] = *(const short8*)(wp + (size_t)oi*16*2048 + kt*32);
#pragma unroll
        for (int mi = 0; mi < 2; ++mi)
            afr[mi] = *(const short8*)(ap + (size_t)mi*16*2048 + kt*32);
#pragma unroll
        for (int oi = 0; oi < 4; ++oi)
#pragma unroll
            for (int mi = 0; mi < 2; ++mi)
                acc[oi][mi] = __builtin_amdgcn_mfma_f32_16x16x32_bf16(
                    wfr[oi], afr[mi], acc[oi][mi], 0, 0, 0);
    }

#pragma unroll
    for (int mi = 0; mi < 2; ++mi) {
        int m = m0 + mi*16 + r;
        int n = m / 49;
        int hw = m % 49;
        float* obase = out + (size_t)n * 256 * 49 + hw;
#pragma unroll
        for (int oi = 0; oi < 4; ++oi) {
#pragma unroll
            for (int jr = 0; jr < 4; ++jr) {
                int o = o0 + oi*16 + q*4 + jr;
                float v = acc[oi][mi][jr] + bfuse[o];
                obase[(size_t)o * 49] = fmaxf(v, 0.f);
            }
        }
    }
}

extern "C" void kernel_launch(void* const* d_in, const int* in_sizes, int n_in,
                              void* d_out, int out_size, void* d_ws, size_t ws_size,
                              hipStream_t stream) {
    const float* feat  = (const float*)d_in[0];   // [256,64,64]
    const float* boxes = (const float*)d_in[1];   // [128,4]
    const float* wf    = (const float*)d_in[2];   // [256,2048]
    const float* bfuse = (const float*)d_in[3];   // [256]
    float* out = (float*)d_out;                   // [128,256,7,7]

    char* ws = (char*)d_ws;
    float* featT          = (float*)ws;                          // 4 MB
    __hip_bfloat16* wfb   = (__hip_bfloat16*)(ws + (4u<<20));    // 1 MB
    __hip_bfloat16* Ap    = (__hip_bfloat16*)(ws + (5u<<20));    // 25.7 MB

    k_transpose<<<256, 256, 0, stream>>>(feat, featT);
    k_cvt<<<2048, 256, 0, stream>>>(wf, wfb, 256*2048);
    k_pool<<<1024, 256, 0, stream>>>(featT, boxes, Ap);
    dim3 g(196, 4);
    k_gemm<<<g, 64, 0, stream>>>(Ap, wfb, bfuse, out);
}

// Round 2
// 113.677 us; speedup vs baseline: 1.0029x; 1.0029x over previous
//
#include <hip/hip_runtime.h>
#include <hip/hip_bf16.h>

#define SCALE (1.0f/16.0f)

typedef __attribute__((ext_vector_type(8))) short short8;
typedef __attribute__((ext_vector_type(4))) short short4v;
typedef __attribute__((ext_vector_type(4))) float f32x4;

// ---------------- K1: transpose features [C=256][4096] -> [4096][256] ----------------
__global__ void k_transpose(const float* __restrict__ feat, float* __restrict__ featT) {
    __shared__ float t[64][65];
    int cb = (blockIdx.x >> 6) << 6;      // c base (0,64,128,192)
    int pb = (blockIdx.x & 63) << 6;      // p base (0..4032 step 64)
    int lx = threadIdx.x & 63, ly = threadIdx.x >> 6;  // ly in 0..3
#pragma unroll
    for (int i = 0; i < 16; ++i) {
        int cl = i*4 + ly;
        t[cl][lx] = feat[(size_t)(cb + cl) * 4096 + pb + lx];
    }
    __syncthreads();
#pragma unroll
    for (int i = 0; i < 16; ++i) {
        int pl = i*4 + ly;
        featT[(size_t)(pb + pl) * 256 + cb + lx] = t[lx][pl];
    }
}

// ---------------- K1b: w_fuse f32 -> bf16 ----------------
__global__ void k_cvt(const float* __restrict__ wf, __hip_bfloat16* __restrict__ wfb, int n) {
    int i = blockIdx.x * blockDim.x + threadIdx.x;
    if (i < n) wfb[i] = __float2bfloat16(wf[i]);
}

// ---------------- K2: context boxes + ROIAlignV2 -> A [6272][2048] bf16 ----------------
// One WAVE per (context box, output pixel). Lane = 4-channel group (float4 taps).
__global__ void __launch_bounds__(256) k_pool(const float* __restrict__ featT,
                                              const float* __restrict__ boxes,
                                              __hip_bfloat16* __restrict__ Ap) {
    int b  = blockIdx.x;                       // context box 0..1023
    int px = blockIdx.y * 4 + (threadIdx.x >> 6);
    if (px >= 49) return;
    int lane = threadIdx.x & 63;

    int off = b >> 7;       // context offset 0..7
    int nb  = b & 127;      // original box index
    int n   = (off << 4) + (nb >> 3);
    int j   = nb & 7;

    float x1 = boxes[nb*4+0], y1 = boxes[nb*4+1];
    float x2 = boxes[nb*4+2], y2 = boxes[nb*4+3];
    float w3 = (x2 - x1) * (1.f/3.f);
    float h3 = (y2 - y1) * (1.f/3.f);
    int t3 = off + (off >= 4 ? 1 : 0);         // 3x3 grid index skipping center
    int ci = t3 / 3, cj = t3 % 3;
    float cx1 = x1 + cj * w3;
    float cy1 = y1 + ci * h3;

    float rx1 = cx1*SCALE - 0.5f;
    float ry1 = cy1*SCALE - 0.5f;
    float bw = ((cx1 + w3)*SCALE - 0.5f - rx1) * (1.f/7.f);
    float bh = ((cy1 + h3)*SCALE - 0.5f - ry1) * (1.f/7.f);

    int h = px / 7, w = px % 7;

    f32x4 s = (f32x4){0.f, 0.f, 0.f, 0.f};
#pragma unroll
    for (int sy = 0; sy < 2; ++sy) {
        float y = ry1 + ((float)h + 0.25f + 0.5f*(float)sy) * bh;
        bool vy = (y >= -1.f) && (y <= 64.f);
        float yc = fminf(fmaxf(y, 0.f), 63.f);
        float ylf = fminf(floorf(yc), 62.f);
        int   yl  = (int)ylf;
        float fy  = yc - ylf;
#pragma unroll
        for (int sx = 0; sx < 2; ++sx) {
            float x = rx1 + ((float)w + 0.25f + 0.5f*(float)sx) * bw;
            bool vx = (x >= -1.f) && (x <= 64.f);
            float xc = fminf(fmaxf(x, 0.f), 63.f);
            float xlf = fminf(floorf(xc), 62.f);
            int   xl  = (int)xlf;
            float fx  = xc - xlf;

            const float* p00 = featT + ((size_t)(yl*64 + xl) * 256 + lane*4);
            f32x4 f00 = *(const f32x4*)(p00);
            f32x4 f01 = *(const f32x4*)(p00 + 256);
            f32x4 f10 = *(const f32x4*)(p00 + 64*256);
            f32x4 f11 = *(const f32x4*)(p00 + 64*256 + 256);
            float w11 = fy*fx, w10 = fy - w11, w01 = fx - w11, w00 = 1.f - fy - fx + w11;
            if (vy && vx)
                s += f00*w00 + f01*w01 + f10*w10 + f11*w11;
        }
    }
    s *= 0.25f;

    short4v pack;
#pragma unroll
    for (int i = 0; i < 4; ++i) {
        __hip_bfloat16 hv = __float2bfloat16(s[i]);
        pack[i] = *reinterpret_cast<short*>(&hv);
    }
    size_t base = ((size_t)(n*49 + px)) * 2048 + (size_t)j * 256 + lane*4;
    *reinterpret_cast<short4v*>(Ap + base) = pack;
}

// ---------------- K3: GEMM out[m][o] = relu(sum_k A[m][k]*wf[o][k] + b[o]) ----------------
// M=6272, N=256, K=2048. Block = 8 waves: (kh in 0..1) x (o-tile 0..3), wave tile 16m x 64o,
// split-K=2 reduced through LDS. Grid = 392 blocks.
__global__ void __launch_bounds__(512) k_gemm(const __hip_bfloat16* __restrict__ Ap,
                                              const __hip_bfloat16* __restrict__ wfb,
                                              const float* __restrict__ bfuse,
                                              float* __restrict__ out) {
    __shared__ float red[4][64][17];

    int tid = threadIdx.x;
    int l = tid & 63;
    int wid = tid >> 6;        // 0..7
    int ot  = wid & 3;         // o-tile
    int kh  = wid >> 2;        // K half
    int r = l & 15, q = l >> 4;
    int m0 = blockIdx.x * 16;
    int o0 = ot * 64;

    f32x4 acc[4];
#pragma unroll
    for (int oi = 0; oi < 4; ++oi) acc[oi] = (f32x4){0.f,0.f,0.f,0.f};

    const __hip_bfloat16* wp = wfb + (size_t)(o0 + r) * 2048 + kh*1024 + q*8;
    const __hip_bfloat16* ap = Ap  + (size_t)(m0 + r) * 2048 + kh*1024 + q*8;

#pragma unroll 2
    for (int kt = 0; kt < 32; ++kt) {
        short8 afr = *(const short8*)(ap + kt*32);
        short8 wfr[4];
#pragma unroll
        for (int oi = 0; oi < 4; ++oi)
            wfr[oi] = *(const short8*)(wp + (size_t)oi*16*2048 + kt*32);
#pragma unroll
        for (int oi = 0; oi < 4; ++oi)
            acc[oi] = __builtin_amdgcn_mfma_f32_16x16x32_bf16(wfr[oi], afr, acc[oi], 0, 0, 0);
    }

    if (kh == 1) {
#pragma unroll
        for (int oi = 0; oi < 4; ++oi)
#pragma unroll
            for (int jr = 0; jr < 4; ++jr)
                red[ot][oi*16 + q*4 + jr][r] = acc[oi][jr];
    }
    __syncthreads();
    if (kh == 0) {
        int m = m0 + r;
        int n = m / 49;
        int hw = m % 49;
        float* obase = out + (size_t)n * 256 * 49 + hw;
#pragma unroll
        for (int oi = 0; oi < 4; ++oi) {
#pragma unroll
            for (int jr = 0; jr < 4; ++jr) {
                int ol = oi*16 + q*4 + jr;
                int o = o0 + ol;
                float v = acc[oi][jr] + red[ot][ol][r] + bfuse[o];
                obase[(size_t)o * 49] = fmaxf(v, 0.f);
            }
        }
    }
}

extern "C" void kernel_launch(void* const* d_in, const int* in_sizes, int n_in,
                              void* d_out, int out_size, void* d_ws, size_t ws_size,
                              hipStream_t stream) {
    const float* feat  = (const float*)d_in[0];   // [256,64,64]
    const float* boxes = (const float*)d_in[1];   // [128,4]
    const float* wf    = (const float*)d_in[2];   // [256,2048]
    const float* bfuse = (const float*)d_in[3];   // [256]
    float* out = (float*)d_out;                   // [128,256,7,7]

    char* ws = (char*)d_ws;
    float* featT          = (float*)ws;                          // 4 MB
    __hip_bfloat16* wfb   = (__hip_bfloat16*)(ws + (4u<<20));    // 1 MB
    __hip_bfloat16* Ap    = (__hip_bfloat16*)(ws + (5u<<20));    // 25.7 MB

    k_transpose<<<256, 256, 0, stream>>>(feat, featT);
    k_cvt<<<2048, 256, 0, stream>>>(wf, wfb, 256*2048);
    dim3 gp(1024, 13);
    k_pool<<<gp, 256, 0, stream>>>(featT, boxes, Ap);
    k_gemm<<<392, 512, 0, stream>>>(Ap, wfb, bfuse, out);
}

// Round 3
// 63.460 us; speedup vs baseline: 1.7964x; 1.7913x over previous
//
#include <hip/hip_runtime.h>
#include <hip/hip_bf16.h>

#define SCALE (1.0f/16.0f)

typedef __attribute__((ext_vector_type(8))) short short8;
typedef __attribute__((ext_vector_type(4))) float f32x4;

__device__ __forceinline__ void gload16(const void* g, void* l) {
    __builtin_amdgcn_global_load_lds(
        (const __attribute__((address_space(1))) unsigned int*)g,
        (__attribute__((address_space(3))) unsigned int*)l, 16, 0, 0);
}

// ---------------- K1: transpose features [C=256][4096] -> [4096][256] ----------------
__global__ void k_transpose(const float* __restrict__ feat, float* __restrict__ featT) {
    __shared__ float t[64][65];
    int cb = (blockIdx.x >> 6) << 6;
    int pb = (blockIdx.x & 63) << 6;
    int lx = threadIdx.x & 63, ly = threadIdx.x >> 6;
#pragma unroll
    for (int i = 0; i < 16; ++i) {
        int cl = i*4 + ly;
        t[cl][lx] = feat[(size_t)(cb + cl) * 4096 + pb + lx];
    }
    __syncthreads();
#pragma unroll
    for (int i = 0; i < 16; ++i) {
        int pl = i*4 + ly;
        featT[(size_t)(pb + pl) * 256 + cb + lx] = t[lx][pl];
    }
}

// ---------------- K1b: w_fuse f32 -> bf16 ----------------
__global__ void k_cvt(const float* __restrict__ wf, __hip_bfloat16* __restrict__ wfb, int n) {
    int i = blockIdx.x * blockDim.x + threadIdx.x;
    if (i < n) wfb[i] = __float2bfloat16(wf[i]);
}

// ---------------- K2: ROIAlign, one block per context box, LDS patch ----------------
// Patch bound: bin size <= 220/48/16 = 0.2865? no: (220/3)/16/7 = 0.655 feat px;
// sample span 6.5*bh <= 4.26 -> <=7 rows x 7 cols incl. +1 bilinear neighbor.
// Input ranges guarantee all samples valid (coords in [-0.5, 63.25]).
__global__ void __launch_bounds__(256) k_pool(const float* __restrict__ featT,
                                              const float* __restrict__ boxes,
                                              __hip_bfloat16* __restrict__ Ap) {
    __shared__ float patch[49*256];   // [ry*7+rx][c]
    int b  = blockIdx.x;
    int off = b >> 7, nb = b & 127;
    int n = (off<<4) + (nb>>3), j = nb & 7;

    float x1 = boxes[nb*4+0], y1 = boxes[nb*4+1];
    float x2 = boxes[nb*4+2], y2 = boxes[nb*4+3];
    float w3 = (x2-x1)*(1.f/3.f), h3 = (y2-y1)*(1.f/3.f);
    int t3 = off + (off>=4 ? 1 : 0);
    int ci = t3/3, cj = t3 - ci*3;
    float rx1 = (x1 + cj*w3)*SCALE - 0.5f;
    float ry1 = (y1 + ci*h3)*SCALE - 0.5f;
    float bw = w3*SCALE*(1.f/7.f);
    float bh = h3*SCALE*(1.f/7.f);

    // patch bounds (sample positions monotone increasing)
    float p0, pc, plf;
    p0 = rx1 + 0.25f*bw; pc = fminf(fmaxf(p0,0.f),63.f); plf = fminf(floorf(pc),62.f);
    int xlo = (int)plf;
    p0 = ry1 + 0.25f*bh; pc = fminf(fmaxf(p0,0.f),63.f); plf = fminf(floorf(pc),62.f);
    int ylo = (int)plf;
    p0 = ry1 + 6.75f*bh; pc = fminf(fmaxf(p0,0.f),63.f); plf = fminf(floorf(pc),62.f);
    int yhi = (int)plf + 1;
    int ny = yhi - ylo + 1;                  // <= 7

    // stage ny x 7 patch rows (f32x4 vector loads, coalesced)
    int nchunk = ny*7*64;
    for (int i = threadIdx.x; i < nchunk; i += 256) {
        int pos = i >> 6, qd = i & 63;
        int ry = pos / 7, rx = pos - ry*7;
        int gr = ylo + ry;
        int gc = min(xlo + rx, 63);
        f32x4 v = *(const f32x4*)(featT + (size_t)(gr*64 + gc)*256 + qd*4);
        *(f32x4*)(patch + pos*256 + qd*4) = v;
    }

    // x-axis sample tables (uniform across threads; statically indexed)
    float xf[14]; int xo[14];
#pragma unroll
    for (int i = 0; i < 14; ++i) {
        float x = rx1 + ((float)i + 0.5f)*0.5f*bw;
        float xc = fminf(fmaxf(x,0.f),63.f);
        float xlf = fminf(floorf(xc),62.f);
        xf[i] = xc - xlf;
        xo[i] = ((int)xlf - xlo) * 256;
    }
    __syncthreads();

    int c = threadIdx.x;
    size_t obase = ((size_t)n*49)*2048 + (size_t)j*256 + c;
    for (int h = 0; h < 7; ++h) {
        float fyv[2]; int ybo[2];
#pragma unroll
        for (int sy = 0; sy < 2; ++sy) {
            float y = ry1 + ((float)(2*h+sy) + 0.5f)*0.5f*bh;
            float yc = fminf(fmaxf(y,0.f),63.f);
            float ylf = fminf(floorf(yc),62.f);
            fyv[sy] = yc - ylf;
            ybo[sy] = ((int)ylf - ylo) * (7*256);
        }
#pragma unroll
        for (int w = 0; w < 7; ++w) {
            float s = 0.f;
#pragma unroll
            for (int sy = 0; sy < 2; ++sy) {
#pragma unroll
                for (int sx = 0; sx < 2; ++sx) {
                    const float* p = patch + ybo[sy] + xo[2*w+sx] + c;
                    float f00 = p[0], f01 = p[256], f10 = p[7*256], f11 = p[7*256+256];
                    float fy = fyv[sy], fx = xf[2*w+sx];
                    float v0 = f00 + fy*(f10-f00);
                    float v1 = f01 + fy*(f11-f01);
                    s += v0 + fx*(v1-v0);
                }
            }
            Ap[obase + (size_t)(h*7+w)*2048] = __float2bfloat16(s*0.25f);
        }
    }
}

// ---------------- K3: LDS-tiled GEMM, BM=128 BN=64 BK=64, 8 waves ----------------
// out[m][o] = relu(sum_k A[m][k]*wf[o][k] + b[o]); M=6272, N=256, K=2048.
// global_load_lds staging with pre-swizzled source; XOR-swizzled ds_read_b128.
__global__ void __launch_bounds__(512) k_gemm(const __hip_bfloat16* __restrict__ Ap,
                                              const __hip_bfloat16* __restrict__ wfb,
                                              const float* __restrict__ bfuse,
                                              float* __restrict__ out) {
    __shared__ char ldsA[2][16384];   // [m 0..127][kb 0..127] swizzled
    __shared__ char ldsB[2][8192];    // [o 0..63][kb 0..127] swizzled
    int tid = threadIdx.x;
    int l = tid & 63, wid = tid >> 6;
    int r = l & 15, q = l >> 4;
    int wm = wid & 3, wo = wid >> 2;
    int m0 = blockIdx.x * 128, o0 = blockIdx.y * 64;

    int lrow = l >> 3;                       // 0..7
    int swz8 = ((l & 7) ^ lrow) << 3;        // pre-swizzled source elem offset
    const __hip_bfloat16* gA = Ap  + (size_t)(m0 + wid*16 + lrow)*2048 + swz8;
    const __hip_bfloat16* gB = wfb + (size_t)(o0 + wid*8  + lrow)*2048 + swz8;

    f32x4 acc[2][2];
#pragma unroll
    for (int oi = 0; oi < 2; ++oi)
#pragma unroll
        for (int mi = 0; mi < 2; ++mi) acc[oi][mi] = (f32x4){0.f,0.f,0.f,0.f};

    auto stage = [&](int buf, int kt) {
        gload16(gA + kt*64,          &ldsA[buf][wid*2048]);
        gload16(gA + kt*64 + 8*2048, &ldsA[buf][wid*2048 + 1024]);
        gload16(gB + kt*64,          &ldsB[buf][wid*1024]);
    };
    auto compute = [&](int buf) {
#pragma unroll
        for (int ks = 0; ks < 2; ++ks) {
            short8 af[2], wfr[2];
#pragma unroll
            for (int mi = 0; mi < 2; ++mi) {
                int ml = wm*32 + mi*16 + r;
                int byo = ml*128 + ((ks*64 + q*16) ^ ((r & 7) << 4));
                af[mi] = *(const short8*)(&ldsA[buf][byo]);
            }
#pragma unroll
            for (int oi = 0; oi < 2; ++oi) {
                int ol = wo*32 + oi*16 + r;
                int byo = ol*128 + ((ks*64 + q*16) ^ ((r & 7) << 4));
                wfr[oi] = *(const short8*)(&ldsB[buf][byo]);
            }
#pragma unroll
            for (int oi = 0; oi < 2; ++oi)
#pragma unroll
                for (int mi = 0; mi < 2; ++mi)
                    acc[oi][mi] = __builtin_amdgcn_mfma_f32_16x16x32_bf16(
                        wfr[oi], af[mi], acc[oi][mi], 0, 0, 0);
        }
    };

    stage(0, 0);
    __syncthreads();
    int cur = 0;
    for (int kt = 0; kt < 31; ++kt) {
        stage(cur ^ 1, kt + 1);
        compute(cur);
        __syncthreads();
        cur ^= 1;
    }
    compute(cur);

#pragma unroll
    for (int mi = 0; mi < 2; ++mi) {
        int m = m0 + wm*32 + mi*16 + r;
        int nn = m / 49, hw = m - nn*49;
        float* ob = out + (size_t)nn*(256*49) + hw;
#pragma unroll
        for (int oi = 0; oi < 2; ++oi) {
#pragma unroll
            for (int jr = 0; jr < 4; ++jr) {
                int o = o0 + wo*32 + oi*16 + q*4 + jr;
                float v = acc[oi][mi][jr] + bfuse[o];
                ob[(size_t)o*49] = fmaxf(v, 0.f);
            }
        }
    }
}

extern "C" void kernel_launch(void* const* d_in, const int* in_sizes, int n_in,
                              void* d_out, int out_size, void* d_ws, size_t ws_size,
                              hipStream_t stream) {
    const float* feat  = (const float*)d_in[0];   // [256,64,64]
    const float* boxes = (const float*)d_in[1];   // [128,4]
    const float* wf    = (const float*)d_in[2];   // [256,2048]
    const float* bfuse = (const float*)d_in[3];   // [256]
    float* out = (float*)d_out;                   // [128,256,7,7]

    char* ws = (char*)d_ws;
    float* featT          = (float*)ws;                          // 4 MB
    __hip_bfloat16* wfb   = (__hip_bfloat16*)(ws + (4u<<20));    // 1 MB
    __hip_bfloat16* Ap    = (__hip_bfloat16*)(ws + (5u<<20));    // 25.7 MB

    k_transpose<<<256, 256, 0, stream>>>(feat, featT);
    k_cvt<<<2048, 256, 0, stream>>>(wf, wfb, 256*2048);
    k_pool<<<1024, 256, 0, stream>>>(featT, boxes, Ap);
    k_gemm<<<dim3(49, 4), 512, 0, stream>>>(Ap, wfb, bfuse, out);
}

// Round 4
// 59.111 us; speedup vs baseline: 1.9286x; 1.0736x over previous
//
#include <hip/hip_runtime.h>
#include <hip/hip_bf16.h>

#define SCALE (1.0f/16.0f)

typedef __attribute__((ext_vector_type(8))) short short8;
typedef __attribute__((ext_vector_type(4))) short short4v;
typedef __attribute__((ext_vector_type(2))) float f32x2;
typedef __attribute__((ext_vector_type(4))) float f32x4;

__device__ __forceinline__ void gload16(const void* g, void* l) {
    __builtin_amdgcn_global_load_lds(
        (const __attribute__((address_space(1))) unsigned int*)g,
        (__attribute__((address_space(3))) unsigned int*)l, 16, 0, 0);
}

// ---------------- K1: transpose features f32 [256][4096] -> bf16 [4096][256] ----------------
__global__ void k_transpose(const float* __restrict__ feat, __hip_bfloat16* __restrict__ featT) {
    __shared__ float t[64][65];
    int cb = (blockIdx.x >> 6) << 6;
    int pb = (blockIdx.x & 63) << 6;
    int lx = threadIdx.x & 63, ly = threadIdx.x >> 6;
#pragma unroll
    for (int i = 0; i < 16; ++i) {
        int cl = i*4 + ly;
        t[cl][lx] = feat[(size_t)(cb + cl) * 4096 + pb + lx];
    }
    __syncthreads();
#pragma unroll
    for (int i = 0; i < 16; ++i) {
        int pl = i*4 + ly;
        featT[(size_t)(pb + pl) * 256 + cb + lx] = __float2bfloat16(t[lx][pl]);
    }
}

// ---------------- K1b: w_fuse f32 -> bf16 (vectorized) ----------------
__global__ void k_cvt(const float* __restrict__ wf, __hip_bfloat16* __restrict__ wfb) {
    int i = blockIdx.x * 256 + threadIdx.x;   // grid 512 -> 131072 f32x4 groups
    f32x4 v = ((const f32x4*)wf)[i];
    short4v o;
#pragma unroll
    for (int u = 0; u < 4; ++u) {
        __hip_bfloat16 h = __float2bfloat16(v[u]);
        o[u] = *reinterpret_cast<short*>(&h);
    }
    ((short4v*)wfb)[i] = o;
}

// ---------------- K2: ROIAlign, block per context box, pair-packed bf16 LDS patch ----------------
__global__ void __launch_bounds__(256) k_pool(const __hip_bfloat16* __restrict__ featT,
                                              const float* __restrict__ boxes,
                                              __hip_bfloat16* __restrict__ Ap) {
    __shared__ unsigned int pairLds[256][51];   // [c][pos] = bf16(f[pos]) | bf16(f[pos+1])<<16
    int b  = blockIdx.x;
    int off = b >> 7, nb = b & 127;
    int n = (off<<4) + (nb>>3), j = nb & 7;

    float x1 = boxes[nb*4+0], y1 = boxes[nb*4+1];
    float x2 = boxes[nb*4+2], y2 = boxes[nb*4+3];
    float w3 = (x2-x1)*(1.f/3.f), h3 = (y2-y1)*(1.f/3.f);
    int t3 = off + (off>=4 ? 1 : 0);
    int ci = t3/3, cj = t3 - ci*3;
    float rx1 = (x1 + cj*w3)*SCALE - 0.5f;
    float ry1 = (y1 + ci*h3)*SCALE - 0.5f;
    float bw = w3*SCALE*(1.f/7.f);
    float bh = h3*SCALE*(1.f/7.f);

    // patch bounds (samples monotone; all coords valid by input ranges)
    float p0, pc, plf;
    p0 = rx1 + 0.25f*bw; pc = fminf(fmaxf(p0,0.f),63.f); plf = fminf(floorf(pc),62.f);
    int xlo = (int)plf;
    p0 = ry1 + 0.25f*bh; pc = fminf(fmaxf(p0,0.f),63.f); plf = fminf(floorf(pc),62.f);
    int ylo = (int)plf;
    p0 = ry1 + 6.75f*bh; pc = fminf(fmaxf(p0,0.f),63.f); plf = fminf(floorf(pc),62.f);
    int ny = (int)plf + 2 - ylo;             // rows ylo .. ylo+ny-1, ny <= 7

    // stage: pair[c][pos] over ny*7 positions, 64 c-quads each
    int nchunk = ny*7*64;
    for (int i = threadIdx.x; i < nchunk; i += 256) {
        int pos = i >> 6, cq = i & 63;
        int ry = pos / 7, rx = pos - ry*7;
        int gr = ylo + ry;
        int gc = min(xlo + rx, 63);
        int gc1 = min(gc + 1, 63);
        short4v lo = *(const short4v*)(featT + ((size_t)(gr*64 + gc )*256 + cq*4));
        short4v hi = *(const short4v*)(featT + ((size_t)(gr*64 + gc1)*256 + cq*4));
#pragma unroll
        for (int u = 0; u < 4; ++u)
            pairLds[cq*4+u][pos] = (unsigned int)(unsigned short)lo[u]
                                 | ((unsigned int)(unsigned short)hi[u] << 16);
    }

    // x sample tables (wave-uniform, statically indexed)
    float xf[14]; int xo[14];
#pragma unroll
    for (int i = 0; i < 14; ++i) {
        float x = rx1 + ((float)i + 0.5f)*0.5f*bw;
        float xc = fminf(fmaxf(x,0.f),63.f);
        float xlf = fminf(floorf(xc),62.f);
        xf[i] = xc - xlf;
        xo[i] = (int)xlf - xlo;
    }
    __syncthreads();

    int c = threadIdx.x;
    const unsigned int* prow = &pairLds[c][0];
    size_t obase = ((size_t)n*49)*2048 + (size_t)j*256 + c;

    for (int h = 0; h < 7; ++h) {
        int rp[2]; float fyv[2];
#pragma unroll
        for (int sy = 0; sy < 2; ++sy) {
            float y = ry1 + ((float)(2*h+sy) + 0.5f)*0.5f*bh;
            float yc = fminf(fmaxf(y,0.f),63.f);
            float ylf = fminf(floorf(yc),62.f);
            fyv[sy] = yc - ylf;
            rp[sy] = ((int)ylf - ylo) * 7;
        }
        f32x2 fypk = {fyv[0], fyv[1]};
#pragma unroll
        for (int w = 0; w < 7; ++w) {
            f32x2 spk = {0.f, 0.f};
#pragma unroll
            for (int sx = 0; sx < 2; ++sx) {
                int xs = 2*w + sx;
                int xc = xo[xs];
                unsigned int a0 = prow[rp[0] + xc];
                unsigned int a1 = prow[rp[0] + 7 + xc];
                unsigned int b0 = prow[rp[1] + xc];
                unsigned int b1 = prow[rp[1] + 7 + xc];
                f32x2 f00 = {__uint_as_float(a0 << 16),        __uint_as_float(b0 << 16)};
                f32x2 f01 = {__uint_as_float(a0 & 0xffff0000u), __uint_as_float(b0 & 0xffff0000u)};
                f32x2 f10 = {__uint_as_float(a1 << 16),        __uint_as_float(b1 << 16)};
                f32x2 f11 = {__uint_as_float(a1 & 0xffff0000u), __uint_as_float(b1 & 0xffff0000u)};
                f32x2 fxv = {xf[xs], xf[xs]};
                f32x2 v0 = f00 + fxv*(f01 - f00);
                f32x2 v1 = f10 + fxv*(f11 - f10);
                spk += v0 + fypk*(v1 - v0);
            }
            Ap[obase + (size_t)(h*7+w)*2048] = __float2bfloat16((spk[0] + spk[1]) * 0.25f);
        }
    }
}

// ---------------- K3: LDS-tiled GEMM, BM=64 BN=64 BK=64, 4 waves, XCD-grouped ----------------
// out[m][o] = relu(sum_k A[m][k]*wf[o][k] + b[o]); M=6272=98*64, N=256=4*64, K=2048.
// Blocks sharing an A-slice are bid===x (mod 8) -> same XCD L2.
__global__ void __launch_bounds__(256) k_gemm(const __hip_bfloat16* __restrict__ Ap,
                                              const __hip_bfloat16* __restrict__ wfb,
                                              const float* __restrict__ bfuse,
                                              float* __restrict__ out) {
    __shared__ char lds[2][16384];   // A [64][128B] swz at 0, B at 8192
    int tid = threadIdx.x;
    int l = tid & 63, wid = tid >> 6;           // 4 waves
    int r = l & 15, q = l >> 4;
    int wm = wid & 1, wo = wid >> 1;            // 2x2 wave grid, 32x32 tiles
    int lrow = l >> 3;
    int sw8 = ((l & 7) ^ lrow) << 3;

    int bid = blockIdx.x;
    int mt, ot;
    if (bid < 384) { int g = bid >> 5, s = bid & 31; mt = g*8 + (s & 7); ot = s >> 3; }
    else           { int rr = bid - 384; mt = 96 + (rr & 1); ot = rr >> 1; }
    int m0 = mt * 64, o0 = ot * 64;

    const __hip_bfloat16* gA = Ap  + (size_t)(m0 + wid*16 + lrow)*2048 + sw8;
    const __hip_bfloat16* gB = wfb + (size_t)(o0 + wid*16 + lrow)*2048 + sw8;

    f32x4 acc[2][2];
#pragma unroll
    for (int oi = 0; oi < 2; ++oi)
#pragma unroll
        for (int mi = 0; mi < 2; ++mi) acc[oi][mi] = (f32x4){0.f,0.f,0.f,0.f};

    auto stage = [&](int buf, int kt) {
        gload16(gA + kt*64,          &lds[buf][wid*2048]);
        gload16(gA + kt*64 + 8*2048, &lds[buf][wid*2048 + 1024]);
        gload16(gB + kt*64,          &lds[buf][8192 + wid*2048]);
        gload16(gB + kt*64 + 8*2048, &lds[buf][8192 + wid*2048 + 1024]);
    };
    auto compute = [&](int buf) {
#pragma unroll
        for (int ks = 0; ks < 2; ++ks) {
            short8 af[2], wfr[2];
#pragma unroll
            for (int mi = 0; mi < 2; ++mi) {
                int ml = wm*32 + mi*16 + r;
                af[mi] = *(const short8*)(&lds[buf][ml*128 + ((ks*64 + q*16) ^ ((ml&7)<<4))]);
            }
#pragma unroll
            for (int oi = 0; oi < 2; ++oi) {
                int ol = wo*32 + oi*16 + r;
                wfr[oi] = *(const short8*)(&lds[buf][8192 + ol*128 + ((ks*64 + q*16) ^ ((ol&7)<<4))]);
            }
#pragma unroll
            for (int oi = 0; oi < 2; ++oi)
#pragma unroll
                for (int mi = 0; mi < 2; ++mi)
                    acc[oi][mi] = __builtin_amdgcn_mfma_f32_16x16x32_bf16(
                        wfr[oi], af[mi], acc[oi][mi], 0, 0, 0);
        }
    };

    stage(0, 0);
    __syncthreads();
    int cur = 0;
    for (int kt = 0; kt < 31; ++kt) {
        stage(cur ^ 1, kt + 1);
        compute(cur);
        __syncthreads();
        cur ^= 1;
    }
    compute(cur);

#pragma unroll
    for (int mi = 0; mi < 2; ++mi) {
        int m = m0 + wm*32 + mi*16 + r;
        int nn = m / 49, hw = m - nn*49;
        float* ob = out + (size_t)nn*(256*49) + hw;
#pragma unroll
        for (int oi = 0; oi < 2; ++oi) {
#pragma unroll
            for (int jr = 0; jr < 4; ++jr) {
                int o = o0 + wo*32 + oi*16 + q*4 + jr;
                float v = acc[oi][mi][jr] + bfuse[o];
                ob[(size_t)o*49] = fmaxf(v, 0.f);
            }
        }
    }
}

extern "C" void kernel_launch(void* const* d_in, const int* in_sizes, int n_in,
                              void* d_out, int out_size, void* d_ws, size_t ws_size,
                              hipStream_t stream) {
    const float* feat  = (const float*)d_in[0];   // [256,64,64]
    const float* boxes = (const float*)d_in[1];   // [128,4]
    const float* wf    = (const float*)d_in[2];   // [256,2048]
    const float* bfuse = (const float*)d_in[3];   // [256]
    float* out = (float*)d_out;                   // [128,256,7,7]

    char* ws = (char*)d_ws;
    __hip_bfloat16* featT = (__hip_bfloat16*)ws;                 // 2 MB
    __hip_bfloat16* wfb   = (__hip_bfloat16*)(ws + (2u<<20));    // 1 MB
    __hip_bfloat16* Ap    = (__hip_bfloat16*)(ws + (3u<<20));    // 24.5 MB

    k_transpose<<<256, 256, 0, stream>>>(feat, featT);
    k_cvt<<<512, 256, 0, stream>>>(wf, wfb);
    k_pool<<<1024, 256, 0, stream>>>(featT, boxes, Ap);
    k_gemm<<<392, 256, 0, stream>>>(Ap, wfb, bfuse, out);
}

// Round 5
// 58.522 us; speedup vs baseline: 1.9480x; 1.0101x over previous
//
#include <hip/hip_runtime.h>
#include <hip/hip_bf16.h>

#define SCALE (1.0f/16.0f)

typedef __attribute__((ext_vector_type(8))) short short8;
typedef __attribute__((ext_vector_type(4))) short short4v;
typedef __attribute__((ext_vector_type(2))) float f32x2;
typedef __attribute__((ext_vector_type(4))) float f32x4;
typedef unsigned int u32;

__device__ __forceinline__ f32x2 unpk(u32 u) {
    f32x2 r;
    r[0] = __uint_as_float(u << 16);
    r[1] = __uint_as_float(u & 0xffff0000u);
    return r;
}
__device__ __forceinline__ u32 pk2bf(f32x2 v) {
    __hip_bfloat16 h0 = __float2bfloat16(v[0]);
    __hip_bfloat16 h1 = __float2bfloat16(v[1]);
    return (u32)*(unsigned short*)&h0 | ((u32)*(unsigned short*)&h1 << 16);
}

// ---------------- K1: transpose features f32 [256][4096] -> bf16 [4096][256] ----------------
__global__ void k_transpose(const float* __restrict__ feat, __hip_bfloat16* __restrict__ featT) {
    __shared__ float t[64][65];
    int cb = (blockIdx.x >> 6) << 6;
    int pb = (blockIdx.x & 63) << 6;
    int lx = threadIdx.x & 63, ly = threadIdx.x >> 6;
#pragma unroll
    for (int i = 0; i < 16; ++i) {
        int cl = i*4 + ly;
        t[cl][lx] = feat[(size_t)(cb + cl) * 4096 + pb + lx];
    }
    __syncthreads();
#pragma unroll
    for (int i = 0; i < 16; ++i) {
        int pl = i*4 + ly;
        featT[(size_t)(pb + pl) * 256 + cb + lx] = __float2bfloat16(t[lx][pl]);
    }
}

// ---------------- K2: permute W f32 [256 o][2048 k] -> bf16 MFMA A-fragment order ----------------
// chunk ch = ((j*16 + t)*8 + s)*64 + l holds 8 bf16: W[o = t*16 + (l&15)][k = j*256 + s*32 + (l>>4)*8 + i]
__global__ void k_permw(const float* __restrict__ wf, __hip_bfloat16* __restrict__ wr) {
    int ch = blockIdx.x * 256 + threadIdx.x;   // 0..65535
    int l = ch & 63;
    int s = (ch >> 6) & 7;
    int t = (ch >> 9) & 15;
    int j = ch >> 13;
    int o = t*16 + (l & 15);
    int k = j*256 + s*32 + (l >> 4)*8;
    const float* src = wf + (size_t)o*2048 + k;
    f32x4 a = *(const f32x4*)src;
    f32x4 b = *(const f32x4*)(src + 4);
    short8 p;
#pragma unroll
    for (int u = 0; u < 4; ++u) {
        __hip_bfloat16 h = __float2bfloat16(a[u]);
        p[u] = *(short*)&h;
    }
#pragma unroll
    for (int u = 0; u < 4; ++u) {
        __hip_bfloat16 h = __float2bfloat16(b[u]);
        p[4+u] = *(short*)&h;
    }
    *((short8*)wr + ch) = p;
}

// ---------------- K3: fused ROIAlign + GEMM ----------------
// Block = (n 0..127, o-half 0..1), 1024 thr (16 waves). Per j: pool context box j (separable FIR:
// patch->X-pass->Y-pass) into P[j&1] (swizzled bf16 [64 hw][256 c]) while MFMAing P[(j-1)&1]
// against streamed W fragments. acc over all j; bias+relu epilogue.
__global__ void __launch_bounds__(1024, 4) k_fused(
    const __hip_bfloat16* __restrict__ featT,
    const float* __restrict__ boxes,
    const __hip_bfloat16* __restrict__ wr,
    const float* __restrict__ bfuse,
    float* __restrict__ out)
{
    __shared__ u32 pxA[128][57];       // patch: [channel-pair][row*8+col] (7 rows x 8 cols)
    __shared__ u32 Xl[49*128];         // X-pass out: [rr*7+w][cp], bf16-pair
    __shared__ char Pl[2][32768];      // pooled tiles [64 hw][256 c] bf16, XOR-swizzled rows
    __shared__ f32x4 xt[7], yt[7];     // 3-tap tables: {base(float), a0, a1, a2}

    int tid = threadIdx.x;
    int n  = blockIdx.x & 127;
    int oh = blockIdx.x >> 7;
    int lane = tid & 63, wid = tid >> 6;      // 16 waves
    int r = lane & 15, q = lane >> 4;
    int t_glob = oh*8 + (wid & 7);            // global o-tile 0..15
    int hh = wid >> 3;                        // hw-half 0..1
    int cp = tid & 127;                       // channel pair
    int e0 = tid >> 7;                        // 0..7 work-strider

    int nb_base = (n & 15) * 8;
    int off = n >> 4;
    int t3 = off + (off >= 4 ? 1 : 0);
    int ci = t3 / 3, cj = t3 - ci*3;

    f32x4 acc[2] = {(f32x4){0,0,0,0}, (f32x4){0,0,0,0}};

    // zero P pad rows 49..63 (read by MFMA hw-tile 3, never stored)
    for (int i = tid; i < 2*15*128; i += 1024) {
        int b = i / (15*128);
        int idx = i - b*(15*128);
        int row = 49 + (idx >> 7), col = idx & 127;
        *(u32*)(Pl[b] + row*512 + col*4) = 0;
    }

    // ---- phase A: box params + 3-tap tables (waves 0,1) + patch stage (waves 2..15) ----
    auto phaseA = [&](int jj) {
        int nbx = nb_base + jj;
        float bx1 = boxes[nbx*4+0], by1 = boxes[nbx*4+1];
        float bx2 = boxes[nbx*4+2], by2 = boxes[nbx*4+3];
        float w3 = (bx2-bx1)*(1.f/3.f), h3 = (by2-by1)*(1.f/3.f);
        float rx1 = (bx1 + cj*w3)*SCALE - 0.5f;
        float ry1 = (by1 + ci*h3)*SCALE - 0.5f;
        float bw2 = w3*(SCALE*(1.f/14.f));    // half-bin
        float bh2 = h3*(SCALE*(1.f/14.f));
        float p0;
        p0 = fminf(fmaxf(rx1 + 0.5f*bw2, 0.f), 63.f);
        int xlo = (int)fminf(floorf(p0), 62.f);
        p0 = fminf(fmaxf(ry1 + 0.5f*bh2, 0.f), 63.f);
        int ylo = (int)fminf(floorf(p0), 62.f);

        if (wid < 2) {
            // sample lanes 0..13, combine lanes 0..6
            bool isy = (wid == 1);
            float base = isy ? ry1 : rx1;
            float step = isy ? bh2 : bw2;
            int lo = isy ? ylo : xlo;
            float p = base + ((float)lane + 0.5f) * step;
            float pc = fminf(fmaxf(p, 0.f), 63.f);
            float fl = fminf(floorf(pc), 62.f);
            float fr = pc - fl;
            float rel = fl - (float)lo;
            float c0 = __shfl(rel, 2*lane);
            float c1 = __shfl(rel, 2*lane+1);
            float f  = __shfl(fr, 2*lane);
            float f2 = __shfl(fr, 2*lane+1);
            float d = c1 - c0;                 // 0 or 1
            float sc = isy ? 0.25f : 1.0f;
            float a0 = sc*((1.f-f) + (1.f-d)*(1.f-f2));
            float a1 = sc*(f + (1.f-d)*f2 + d*(1.f-f2));
            float a2 = sc*(d*f2);
            if (lane < 7) {
                f32x4 e; e[0] = c0; e[1] = a0; e[2] = a1; e[3] = a2;
                if (isy) yt[lane] = e; else xt[lane] = e;
            }
        } else {
            int stid = tid - 128;
            for (int i = stid; i < 56*64; i += 896) {
                int pos = i >> 6, cq = i & 63;
                int rr = pos >> 3, cc = pos & 7;
                int gr = min(ylo + rr, 63), gc = min(xlo + cc, 63);
                short4v v = *(const short4v*)(featT + ((size_t)(gr*64+gc)*256 + cq*4));
                pxA[2*cq][pos]   = (u32)(unsigned short)v[0] | ((u32)(unsigned short)v[1] << 16);
                pxA[2*cq+1][pos] = (u32)(unsigned short)v[2] | ((u32)(unsigned short)v[3] << 16);
            }
        }
    };

    // ---- X pass: Xl[rr*7+w][cp] = sum_dc xt[w].a[dc] * patch[rr][c0+dc] ----
    auto xpass = [&]() {
        const u32* prow = &pxA[cp][0];
        for (int e = e0; e < 49; e += 8) {
            int rr = e / 7, w = e - rr*7;
            f32x4 tx = xt[w];
            int pos = rr*8 + (int)tx[0];
            f32x2 F0 = unpk(prow[pos]);
            f32x2 F1 = unpk(prow[pos+1]);
            f32x2 F2 = unpk(prow[pos+2]);
            f32x2 X = tx[1]*F0 + tx[2]*F1 + tx[3]*F2;
            Xl[e*128 + cp] = pk2bf(X);
        }
    };

    // ---- Y pass -> P[buf] ----
    auto ypass = [&](int buf) {
        char* pdst = Pl[buf];
        for (int hw = e0; hw < 49; hw += 8) {
            int h = hw / 7, w = hw - h*7;
            f32x4 ty = yt[h];
            int r0 = (int)ty[0];
            int i2 = min(r0 + 2, 6);
            f32x2 X0 = unpk(Xl[(r0*7 + w)*128 + cp]);
            f32x2 X1 = unpk(Xl[((r0+1)*7 + w)*128 + cp]);
            f32x2 X2 = unpk(Xl[(i2*7 + w)*128 + cp]);
            f32x2 v = ty[1]*X0 + ty[2]*X1 + ty[3]*X2;   // 0.25 folded into ty
            *(u32*)(pdst + hw*512 + ((cp*4) ^ ((hw & 7) << 4))) = pk2bf(v);
        }
    };

    // ---- GEMM step j: acc += Wfrag(j) x P[buf] ----
    auto gemm = [&](int j, int buf) {
        const short8* wbase = (const short8*)wr + (size_t)((j*16 + t_glob)*8)*64 + lane;
        short8 wfrag[8];
#pragma unroll
        for (int s = 0; s < 8; ++s) wfrag[s] = wbase[s*64];
#pragma unroll
        for (int s = 0; s < 8; ++s) {
#pragma unroll
            for (int ht = 0; ht < 2; ++ht) {
                int row = (hh*2 + ht)*16 + r;
                int byo = row*512 + ((s*64 + q*16) ^ ((r & 7) << 4));
                short8 pf = *(const short8*)(Pl[buf] + byo);
                acc[ht] = __builtin_amdgcn_mfma_f32_16x16x32_bf16(wfrag[s], pf, acc[ht], 0, 0, 0);
            }
        }
    };

    // prologue: pool box 0 into P[0]
    phaseA(0);
    __syncthreads();
    xpass();
    __syncthreads();
    ypass(0);
    __syncthreads();

    for (int j = 0; j < 8; ++j) {
        gemm(j, j & 1);
        if (j < 7) phaseA(j+1);
        __syncthreads();
        if (j < 7) xpass();
        __syncthreads();
        if (j < 7) ypass((j+1) & 1);
        __syncthreads();
    }

    // epilogue: bias + relu, out[n][o][hw]
#pragma unroll
    for (int ht = 0; ht < 2; ++ht) {
        int hw = (hh*2 + ht)*16 + r;
        if (hw < 49) {
#pragma unroll
            for (int jr = 0; jr < 4; ++jr) {
                int o = t_glob*16 + q*4 + jr;
                float v = acc[ht][jr] + bfuse[o];
                out[((size_t)n*256 + o)*49 + hw] = fmaxf(v, 0.f);
            }
        }
    }
}

extern "C" void kernel_launch(void* const* d_in, const int* in_sizes, int n_in,
                              void* d_out, int out_size, void* d_ws, size_t ws_size,
                              hipStream_t stream) {
    const float* feat  = (const float*)d_in[0];   // [256,64,64]
    const float* boxes = (const float*)d_in[1];   // [128,4]
    const float* wf    = (const float*)d_in[2];   // [256,2048]
    const float* bfuse = (const float*)d_in[3];   // [256]
    float* out = (float*)d_out;                   // [128,256,7,7]

    char* ws = (char*)d_ws;
    __hip_bfloat16* featT = (__hip_bfloat16*)ws;                 // 2 MB
    __hip_bfloat16* wr    = (__hip_bfloat16*)(ws + (2u<<20));    // 1 MB (permuted W)

    k_transpose<<<256, 256, 0, stream>>>(feat, featT);
    k_permw<<<256, 256, 0, stream>>>(wf, wr);
    k_fused<<<256, 1024, 0, stream>>>(featT, boxes, wr, bfuse, out);
}

// Round 6
// 45.809 us; speedup vs baseline: 2.4886x; 1.2775x over previous
//
#include <hip/hip_runtime.h>
#include <hip/hip_bf16.h>

#define SCALE (1.0f/16.0f)

typedef __attribute__((ext_vector_type(8))) short short8;
typedef __attribute__((ext_vector_type(4))) short short4v;
typedef __attribute__((ext_vector_type(2))) float f32x2;
typedef __attribute__((ext_vector_type(4))) float f32x4;
typedef __attribute__((ext_vector_type(16))) float f32x16;
typedef unsigned int u32;

__device__ __forceinline__ f32x2 unpk(u32 u) {
    f32x2 r;
    r[0] = __uint_as_float(u << 16);
    r[1] = __uint_as_float(u & 0xffff0000u);
    return r;
}
__device__ __forceinline__ u32 pk2bf(f32x2 v) {
    __hip_bfloat16 h0 = __float2bfloat16(v[0]);
    __hip_bfloat16 h1 = __float2bfloat16(v[1]);
    return (u32)*(unsigned short*)&h0 | ((u32)*(unsigned short*)&h1 << 16);
}

// ---------------- K1: transpose features f32 [256][4096] -> bf16 [4096][256] ----------------
__global__ void k_transpose(const float* __restrict__ feat, __hip_bfloat16* __restrict__ featT) {
    __shared__ float t[64][65];
    int cb = (blockIdx.x >> 6) << 6;
    int pb = (blockIdx.x & 63) << 6;
    int lx = threadIdx.x & 63, ly = threadIdx.x >> 6;
#pragma unroll
    for (int i = 0; i < 16; ++i) {
        int cl = i*4 + ly;
        t[cl][lx] = feat[(size_t)(cb + cl) * 4096 + pb + lx];
    }
    __syncthreads();
#pragma unroll
    for (int i = 0; i < 16; ++i) {
        int pl = i*4 + ly;
        featT[(size_t)(pb + pl) * 256 + cb + lx] = __float2bfloat16(t[lx][pl]);
    }
}

// ---------------- K2: permute W -> 32x32x16 MFMA A-fragment order ----------------
// chunk ch = ((j*8 + ot)*16 + sk)*64 + l : 8 bf16 of W[o = ot*32 + (l&31)][k = j*256 + sk*16 + (l>>5)*8 + i]
__global__ void k_permw(const float* __restrict__ wf, __hip_bfloat16* __restrict__ wr) {
    int ch = blockIdx.x * 256 + threadIdx.x;   // 65536 chunks
    int l  = ch & 63;
    int sk = (ch >> 6) & 15;
    int ot = (ch >> 10) & 7;
    int j  = ch >> 13;
    int o = ot*32 + (l & 31);
    int k = j*256 + sk*16 + (l >> 5)*8;
    const float* src = wf + (size_t)o*2048 + k;
    f32x4 a = *(const f32x4*)src;
    f32x4 b = *(const f32x4*)(src + 4);
    short8 p;
#pragma unroll
    for (int u = 0; u < 4; ++u) {
        __hip_bfloat16 h = __float2bfloat16(a[u]); p[u] = *(short*)&h;
    }
#pragma unroll
    for (int u = 0; u < 4; ++u) {
        __hip_bfloat16 h = __float2bfloat16(b[u]); p[4+u] = *(short*)&h;
    }
    *((short8*)wr + ch) = p;
}

// ---------------- K3: fused ROIAlign + GEMM ----------------
// Block = (n 0..127, hw-half 0..1), 1024 thr = 16 waves = 8 o-tiles x 2 k-halves.
// Per j: pool box j directly from featT (9-tap separable FIR, tables in LDS) into Pl
// [32 hw][256 c] bf16 swizzled; then each wave does 8 MFMA 32x32x16 (its k-half).
// Split-K reduced via LDS at the end. 2 barriers per j.
__global__ void __launch_bounds__(1024, 4) k_fused(
    const __hip_bfloat16* __restrict__ featT,
    const float* __restrict__ boxes,
    const __hip_bfloat16* __restrict__ wr,
    const float* __restrict__ bfuse,
    float* __restrict__ out)
{
    __shared__ char Pl[16384];            // [32 hw][512 B] swizzled bf16 pairs
    __shared__ float red[8*64*16];        // split-K reduce buffer (32 KB)
    __shared__ f32x4 xt[7], yt[7];        // {pos0(abs,float), a0, a1, a2}

    int tid = threadIdx.x;
    int n  = blockIdx.x >> 1;
    int hh = blockIdx.x & 1;
    int hw0 = hh * 25;
    int HWn = hh ? 24 : 25;
    int lane = tid & 63, wid = tid >> 6;
    int ot = wid & 7, kh = wid >> 3;
    int cp = tid & 127, e0 = tid >> 7;

    int nb_base = (n & 15) * 8;
    int off = n >> 4;
    int t3 = off + (off >= 4 ? 1 : 0);
    int ci = t3 / 3, cj = t3 - ci*3;

    f32x16 acc;
#pragma unroll
    for (int i = 0; i < 16; ++i) acc[i] = 0.f;

    const u32* fp32 = (const u32*)featT;  // pair view: idx = pixel*128 + cp

    // ---- per-j 3-tap separable tables (waves 14: x, 15: y) ----
    auto tables = [&](int jj) {
        if (wid < 14) return;
        bool isy = (wid == 15);
        int nbx = nb_base + jj;
        float bx1 = boxes[nbx*4+0], by1 = boxes[nbx*4+1];
        float bx2 = boxes[nbx*4+2], by2 = boxes[nbx*4+3];
        float w3 = (bx2-bx1)*(1.f/3.f), h3 = (by2-by1)*(1.f/3.f);
        float org  = isy ? (by1 + ci*h3)*SCALE - 0.5f : (bx1 + cj*w3)*SCALE - 0.5f;
        float step = (isy ? h3 : w3) * (SCALE*(1.f/14.f));   // half-bin
        float sc = isy ? 0.25f : 1.f;
        float p = org + ((float)lane + 0.5f)*step;
        float pc = fminf(fmaxf(p, 0.f), 63.f);
        float fl = fminf(floorf(pc), 62.f);
        float fr = pc - fl;
        float c0 = __shfl(fl, 2*lane);
        float c1 = __shfl(fl, 2*lane+1);
        float f  = __shfl(fr, 2*lane);
        float f2 = __shfl(fr, 2*lane+1);
        float d = c1 - c0;                 // 0 or 1
        float a0 = sc*((1.f-f) + (1.f-d)*(1.f-f2));
        float a1 = sc*(f + (1.f-d)*f2 + d*(1.f-f2));
        float a2 = sc*(d*f2);
        if (lane < 7) {
            f32x4 e; e[0] = c0; e[1] = a0; e[2] = a1; e[3] = a2;
            if (isy) yt[lane] = e; else xt[lane] = e;
        }
    };

    // ---- pool current box into Pl (direct global 9-tap) ----
    auto pool = [&]() {
        for (int e = e0; e < HWn; e += 8) {
            int g = hw0 + e;
            int h = (g*37) >> 8;           // g/7 for g<=48
            int w = g - h*7;
            f32x4 tx = xt[w], ty = yt[h];
            int x0 = (int)tx[0], y0 = (int)ty[0];
            int x2 = min(x0 + 2, 63), y2 = min(y0 + 2, 63);
            int r0 = (y0*64 + x0)*128 + cp;
            int r1 = r0 + 8192;
            int r2 = (y2*64 + x0)*128 + cp;
            int dx2 = (x2 - x0)*128;
            u32 F00 = fp32[r0], F01 = fp32[r0+128], F02 = fp32[r0+dx2];
            u32 F10 = fp32[r1], F11 = fp32[r1+128], F12 = fp32[r1+dx2];
            u32 F20 = fp32[r2], F21 = fp32[r2+128], F22 = fp32[r2+dx2];
            f32x2 row0 = tx[1]*unpk(F00) + tx[2]*unpk(F01) + tx[3]*unpk(F02);
            f32x2 row1 = tx[1]*unpk(F10) + tx[2]*unpk(F11) + tx[3]*unpk(F12);
            f32x2 row2 = tx[1]*unpk(F20) + tx[2]*unpk(F21) + tx[3]*unpk(F22);
            f32x2 v = ty[1]*row0 + ty[2]*row1 + ty[3]*row2;   // 0.25 folded into yt
            *(u32*)(Pl + e*512 + ((cp*4) ^ ((e & 7) << 4))) = pk2bf(v);
        }
    };

    // ---- GEMM step j: acc += W(j, ot, k-half) x Pl ----
    auto gemm = [&](int j) {
        const short8* wb = (const short8*)wr + ((size_t)(((j*8 + ot)*16) + kh*8)*64 + lane);
        int row = lane & 31;
#pragma unroll
        for (int sb = 0; sb < 2; ++sb) {
            short8 wf4[4];
#pragma unroll
            for (int s4 = 0; s4 < 4; ++s4) wf4[s4] = wb[(sb*4 + s4)*64];
#pragma unroll
            for (int s4 = 0; s4 < 4; ++s4) {
                int sk = kh*8 + sb*4 + s4;
                int byo = row*512 + (((sk*32) + (lane >> 5)*16) ^ ((row & 7) << 4));
                short8 pf = *(const short8*)(Pl + byo);
                acc = __builtin_amdgcn_mfma_f32_32x32x16_bf16(wf4[s4], pf, acc, 0, 0, 0);
            }
        }
    };

    tables(0);
    __syncthreads();
    pool();
    __syncthreads();
    for (int j = 0; j < 8; ++j) {
        gemm(j);
        if (j < 7) tables(j+1);
        __syncthreads();
        if (j < 7) { pool(); __syncthreads(); }
    }

    // ---- split-K reduce + epilogue ----
    if (kh == 1) {
        float* rb = &red[(ot*64 + lane)*16];
#pragma unroll
        for (int q4 = 0; q4 < 4; ++q4) {
            f32x4 t;
#pragma unroll
            for (int i = 0; i < 4; ++i) t[i] = acc[q4*4 + i];
            *(f32x4*)(rb + q4*4) = t;
        }
    }
    __syncthreads();
    if (kh == 0) {
        const float* rb = &red[(ot*64 + lane)*16];
        int hwl = lane & 31;
        int g = hw0 + hwl;
        bool ok = hwl < HWn;
#pragma unroll
        for (int reg = 0; reg < 16; ++reg) {
            int ol = (reg & 3) + 8*(reg >> 2) + 4*(lane >> 5);
            int o = ot*32 + ol;
            float v = acc[reg] + rb[reg] + bfuse[o];
            if (ok) out[((size_t)n*256 + o)*49 + g] = fmaxf(v, 0.f);
        }
    }
}

extern "C" void kernel_launch(void* const* d_in, const int* in_sizes, int n_in,
                              void* d_out, int out_size, void* d_ws, size_t ws_size,
                              hipStream_t stream) {
    const float* feat  = (const float*)d_in[0];   // [256,64,64]
    const float* boxes = (const float*)d_in[1];   // [128,4]
    const float* wf    = (const float*)d_in[2];   // [256,2048]
    const float* bfuse = (const float*)d_in[3];   // [256]
    float* out = (float*)d_out;                   // [128,256,7,7]

    char* ws = (char*)d_ws;
    __hip_bfloat16* featT = (__hip_bfloat16*)ws;                 // 2 MB
    __hip_bfloat16* wr    = (__hip_bfloat16*)(ws + (2u<<20));    // 1 MB (permuted W)

    k_transpose<<<256, 256, 0, stream>>>(feat, featT);
    k_permw<<<256, 256, 0, stream>>>(wf, wr);
    k_fused<<<256, 1024, 0, stream>>>(featT, boxes, wr, bfuse, out);
}